// Round 4
// baseline (780.576 us; speedup 1.0000x reference)
//
#include <hip/hip_runtime.h>

#define N_NODES 100000
#define N_EDGES 3200000
#define F_X 24
#define F_S 8
#define D_IN 32   // F_X + F_S
#define H_DIM 64
#define F_OUT 32

#define NPB 128                  // nodes per bucket (power of 2 -> bkt = dst>>7)
#define NBKT 782                 // ceil(100000/128); last bucket has 32 nodes
#define BCAP 4608                // per-bucket slot capacity (mean 4096 + 8 sigma)
#define P1_EPT 16                // edges per thread in partition
#define P1_EPB (256 * P1_EPT)    // 4096 edges per block
#define P1_BLOCKS ((N_EDGES + P1_EPB - 1) / P1_EPB)   // 782

// float -> bf16 (round-to-nearest-even), returns low 16 bits
__device__ __forceinline__ unsigned bf16_rne(float f) {
    unsigned u = __float_as_uint(f);
    return (u + 0x7fffu + ((u >> 16) & 1u)) >> 16;
}

// ---------------------------------------------------------------------------
// Kernel 1: per-node MLP -> bf16 y table ([N_NODES, 32] bf16 = 16 uints/row)
// ---------------------------------------------------------------------------
__global__ __launch_bounds__(256) void node_mlp_kernel(
    const float* __restrict__ x, const float* __restrict__ scalars,
    const float* __restrict__ W1, const float* __restrict__ b1,
    const float* __restrict__ W2, const float* __restrict__ b2,
    unsigned* __restrict__ y)
{
    __shared__ float sW1[D_IN * H_DIM];
    __shared__ float sW2[H_DIM * F_OUT];
    __shared__ float sb1[H_DIM];
    __shared__ float sb2[F_OUT];
    __shared__ float ss[F_S];

    const int tid = threadIdx.x;
    for (int i = tid; i < D_IN * H_DIM; i += 256) sW1[i] = W1[i];
    for (int i = tid; i < H_DIM * F_OUT; i += 256) sW2[i] = W2[i];
    if (tid < H_DIM)  sb1[tid] = b1[tid];
    if (tid < F_OUT)  sb2[tid] = b2[tid];
    if (tid < F_S)    ss[tid]  = scalars[tid];
    __syncthreads();

    const int v = blockIdx.x * 256 + tid;
    if (v >= N_NODES) return;

    float h[D_IN];
    const float4* xr = reinterpret_cast<const float4*>(x + (size_t)v * F_X);
    #pragma unroll
    for (int i = 0; i < F_X / 4; ++i) {
        float4 t = xr[i];
        h[i * 4 + 0] = t.x; h[i * 4 + 1] = t.y;
        h[i * 4 + 2] = t.z; h[i * 4 + 3] = t.w;
    }
    #pragma unroll
    for (int i = 0; i < F_S; ++i) h[F_X + i] = ss[i];

    float hid[H_DIM];
    #pragma unroll
    for (int l = 0; l < H_DIM; ++l) hid[l] = sb1[l];
    #pragma unroll
    for (int k = 0; k < D_IN; ++k) {
        const float hk = h[k];
        #pragma unroll
        for (int l = 0; l < H_DIM; ++l)
            hid[l] = fmaf(hk, sW1[k * H_DIM + l], hid[l]);
    }
    #pragma unroll
    for (int l = 0; l < H_DIM; ++l) hid[l] = fmaxf(hid[l], 0.0f);

    float o[F_OUT];
    #pragma unroll
    for (int j = 0; j < F_OUT; ++j) o[j] = sb2[j];
    #pragma unroll
    for (int l = 0; l < H_DIM; ++l) {
        const float hl = hid[l];
        #pragma unroll
        for (int j = 0; j < F_OUT; ++j)
            o[j] = fmaf(hl, sW2[l * F_OUT + j], o[j]);
    }

    unsigned pk[16];
    #pragma unroll
    for (int k = 0; k < 16; ++k)
        pk[k] = bf16_rne(o[2 * k]) | (bf16_rne(o[2 * k + 1]) << 16);
    uint4* yr = reinterpret_cast<uint4*>(y + (size_t)v * 16);
    #pragma unroll
    for (int q = 0; q < 4; ++q)
        yr[q] = make_uint4(pk[q * 4], pk[q * 4 + 1], pk[q * 4 + 2], pk[q * 4 + 3]);
}

// ---------------------------------------------------------------------------
// Kernel 2: partition edges into 782 dst-buckets.
// Block-aggregated reservation: LDS rank assignment, then ONE global atomic
// per (block,bucket) on a line-padded cursor, then packed scatter writes.
// ---------------------------------------------------------------------------
__global__ __launch_bounds__(256) void p1_partition(
    const int* __restrict__ ei,
    int* __restrict__ cursor,        // [NBKT*16] ints, one counter per 64B line
    unsigned* __restrict__ bbuf)     // [NBKT * BCAP] packed edges
{
    __shared__ int cnt[NBKT];
    __shared__ int base[NBKT];
    const int tid = threadIdx.x;
    for (int i = tid; i < NBKT; i += 256) cnt[i] = 0;
    __syncthreads();

    const int e0 = blockIdx.x * P1_EPB + tid;
    unsigned pk[P1_EPT];
    int meta[P1_EPT];                // bkt (10b) | rank<<10 (12b)
    #pragma unroll
    for (int k = 0; k < P1_EPT; ++k) {
        const int e = e0 + k * 256;  // coalesced stream per iteration
        if (e < N_EDGES) {
            const int src = ei[e];
            const int dst = ei[N_EDGES + e];
            const int bkt = dst >> 7;
            const int rank = atomicAdd(&cnt[bkt], 1);
            pk[k]   = (unsigned)src | ((unsigned)(dst & 127) << 17);
            meta[k] = bkt | (rank << 10);
        } else {
            meta[k] = -1;
        }
    }
    __syncthreads();

    for (int i = tid; i < NBKT; i += 256) {
        const int c = cnt[i];
        base[i] = c ? atomicAdd(&cursor[i * 16], c) : 0;
    }
    __syncthreads();

    #pragma unroll
    for (int k = 0; k < P1_EPT; ++k) {
        if (meta[k] >= 0) {
            const int bkt = meta[k] & 1023;
            const int idx = base[bkt] + (meta[k] >> 10);
            if (idx < BCAP)
                bbuf[(size_t)bkt * BCAP + idx] = pk[k];
        }
    }
}

// ---------------------------------------------------------------------------
// Kernel 3: fused per-bucket aggregation. One block per bucket; 128x32 f32
// LDS accumulator; 4-lane groups: lane c reads uint4 chunk c of y[src] and
// does 8 LDS float atomics with per-group rotation (2-way bank alias = free).
// Coalesced float4 output write; no d_out memset needed.
// ---------------------------------------------------------------------------
__global__ __launch_bounds__(256) void p2_aggregate(
    const int* __restrict__ cursor,
    const unsigned* __restrict__ bbuf,
    const unsigned* __restrict__ y,
    float* __restrict__ out)
{
    __shared__ float acc[NPB * F_OUT];   // 16 KB
    const int tid = threadIdx.x;
    const int b = blockIdx.x;

    for (int i = tid; i < NPB * F_OUT; i += 256) acc[i] = 0.0f;
    __syncthreads();

    int nE = cursor[b * 16];
    if (nE > BCAP) nE = BCAP;
    const unsigned* ebase = bbuf + (size_t)b * BCAP;

    const int g = tid >> 2;     // group 0..63
    const int c = tid & 3;      // uint4 chunk
    const int rot = g & 7;

    for (int i = g; i < nE; i += 64) {
        const unsigned w = ebase[i];                 // same addr across group
        const int src = (int)(w & 0x1FFFFu);
        const int dl  = (int)((w >> 17) & 127u);
        const uint4 q = reinterpret_cast<const uint4*>(y + (size_t)src * 16)[c];
        const unsigned qq[4] = {q.x, q.y, q.z, q.w};
        float* arow = acc + dl * F_OUT + c * 8;
        #pragma unroll
        for (int k = 0; k < 8; ++k) {
            const int kk = (k + rot) & 7;
            const unsigned u = qq[kk >> 1];
            const float f = (kk & 1) ? __uint_as_float(u & 0xFFFF0000u)
                                     : __uint_as_float(u << 16);
            atomicAdd(&arow[kk], f);
        }
    }
    __syncthreads();

    const int vbase = b * NPB;
    const int nrows = min(NPB, N_NODES - vbase);
    const int nflt4 = nrows * (F_OUT / 4);
    float4* o4 = reinterpret_cast<float4*>(out + (size_t)vbase * F_OUT);
    const float4* a4 = reinterpret_cast<const float4*>(acc);
    for (int i = tid; i < nflt4; i += 256) o4[i] = a4[i];
}

extern "C" void kernel_launch(void* const* d_in, const int* in_sizes, int n_in,
                              void* d_out, int out_size, void* d_ws, size_t ws_size,
                              hipStream_t stream) {
    const float* x       = (const float*)d_in[0];
    const float* scalars = (const float*)d_in[1];
    const int*   ei      = (const int*)d_in[2];
    const float* W1      = (const float*)d_in[3];
    const float* b1      = (const float*)d_in[4];
    const float* W2      = (const float*)d_in[5];
    const float* b2      = (const float*)d_in[6];
    float* out = (float*)d_out;

    // Workspace layout (64B aligned), total ~20.9 MB
    char* ws = (char*)d_ws;
    unsigned* y      = (unsigned*)ws;                    //  6,400,000 B
    int*      cursor = (int*)(ws + 6400000);             //     50,048 B (782*64)
    unsigned* bbuf   = (unsigned*)(ws + 6450048);        // 14,417,920 B (782*4608*4)

    // 1) per-node MLP -> bf16 y
    node_mlp_kernel<<<(N_NODES + 255) / 256, 256, 0, stream>>>(
        x, scalars, W1, b1, W2, b2, y);

    // 2) zero bucket cursors (3.2K of counters, line-padded)
    hipMemsetAsync(cursor, 0, (size_t)NBKT * 16 * sizeof(int), stream);

    // 3) partition edges into buckets
    p1_partition<<<P1_BLOCKS, 256, 0, stream>>>(ei, cursor, bbuf);

    // 4) fused per-bucket gather + accumulate + write
    p2_aggregate<<<NBKT, 256, 0, stream>>>(cursor, bbuf, y, out);
}

// Round 5
// 695.586 us; speedup vs baseline: 1.1222x; 1.1222x over previous
//
#include <hip/hip_runtime.h>

#define N_NODES 100000
#define N_EDGES 3200000
#define F_X 24
#define F_S 8
#define D_IN 32   // F_X + F_S
#define H_DIM 64
#define F_OUT 32

#define NPB 64                   // nodes per bucket (bkt = dst>>6)
#define NBKT 1563                // ceil(100000/64); last bucket has 32 nodes
#define BCAP 2432                // per-bucket capacity (mean 2048 + ~8.5 sigma)
#define P1_EPT 32                // edges per thread in partition
#define P1_EPB (256 * P1_EPT)    // 8192 edges per block
#define P1_BLOCKS ((N_EDGES + P1_EPB - 1) / P1_EPB)   // 391

// float -> bf16 (round-to-nearest-even), returns low 16 bits
__device__ __forceinline__ unsigned bf16_rne(float f) {
    unsigned u = __float_as_uint(f);
    return (u + 0x7fffu + ((u >> 16) & 1u)) >> 16;
}

// ---------------------------------------------------------------------------
// Kernel 1: per-node MLP -> bf16 y table ([N_NODES, 32] bf16 = 16 uints/row)
// ---------------------------------------------------------------------------
__global__ __launch_bounds__(256) void node_mlp_kernel(
    const float* __restrict__ x, const float* __restrict__ scalars,
    const float* __restrict__ W1, const float* __restrict__ b1,
    const float* __restrict__ W2, const float* __restrict__ b2,
    unsigned* __restrict__ y)
{
    __shared__ float sW1[D_IN * H_DIM];
    __shared__ float sW2[H_DIM * F_OUT];
    __shared__ float sb1[H_DIM];
    __shared__ float sb2[F_OUT];
    __shared__ float ss[F_S];

    const int tid = threadIdx.x;
    for (int i = tid; i < D_IN * H_DIM; i += 256) sW1[i] = W1[i];
    for (int i = tid; i < H_DIM * F_OUT; i += 256) sW2[i] = W2[i];
    if (tid < H_DIM)  sb1[tid] = b1[tid];
    if (tid < F_OUT)  sb2[tid] = b2[tid];
    if (tid < F_S)    ss[tid]  = scalars[tid];
    __syncthreads();

    const int v = blockIdx.x * 256 + tid;
    if (v >= N_NODES) return;

    float h[D_IN];
    const float4* xr = reinterpret_cast<const float4*>(x + (size_t)v * F_X);
    #pragma unroll
    for (int i = 0; i < F_X / 4; ++i) {
        float4 t = xr[i];
        h[i * 4 + 0] = t.x; h[i * 4 + 1] = t.y;
        h[i * 4 + 2] = t.z; h[i * 4 + 3] = t.w;
    }
    #pragma unroll
    for (int i = 0; i < F_S; ++i) h[F_X + i] = ss[i];

    float hid[H_DIM];
    #pragma unroll
    for (int l = 0; l < H_DIM; ++l) hid[l] = sb1[l];
    #pragma unroll
    for (int k = 0; k < D_IN; ++k) {
        const float hk = h[k];
        #pragma unroll
        for (int l = 0; l < H_DIM; ++l)
            hid[l] = fmaf(hk, sW1[k * H_DIM + l], hid[l]);
    }
    #pragma unroll
    for (int l = 0; l < H_DIM; ++l) hid[l] = fmaxf(hid[l], 0.0f);

    float o[F_OUT];
    #pragma unroll
    for (int j = 0; j < F_OUT; ++j) o[j] = sb2[j];
    #pragma unroll
    for (int l = 0; l < H_DIM; ++l) {
        const float hl = hid[l];
        #pragma unroll
        for (int j = 0; j < F_OUT; ++j)
            o[j] = fmaf(hl, sW2[l * F_OUT + j], o[j]);
    }

    unsigned pk[16];
    #pragma unroll
    for (int k = 0; k < 16; ++k)
        pk[k] = bf16_rne(o[2 * k]) | (bf16_rne(o[2 * k + 1]) << 16);
    uint4* yr = reinterpret_cast<uint4*>(y + (size_t)v * 16);
    #pragma unroll
    for (int q = 0; q < 4; ++q)
        yr[q] = make_uint4(pk[q * 4], pk[q * 4 + 1], pk[q * 4 + 2], pk[q * 4 + 3]);
}

// ---------------------------------------------------------------------------
// Kernel 2: partition edges into 1563 dst-buckets (64 nodes each).
// Block-aggregated reservation: LDS rank assignment, one global atomic per
// (block,bucket) on a line-padded cursor, then packed scatter writes
// (per-(block,bucket) runs are consecutive -> decent line utilization).
// ---------------------------------------------------------------------------
__global__ __launch_bounds__(256) void p1_partition(
    const int* __restrict__ ei,
    int* __restrict__ cursor,        // [NBKT*16] ints, one counter per 64B line
    unsigned* __restrict__ bbuf)     // [NBKT * BCAP] packed edges
{
    __shared__ int cnt[NBKT];
    __shared__ int base[NBKT];
    const int tid = threadIdx.x;
    for (int i = tid; i < NBKT; i += 256) cnt[i] = 0;
    __syncthreads();

    const int e0 = blockIdx.x * P1_EPB + tid;
    unsigned pk[P1_EPT];
    int meta[P1_EPT];                // bkt (11b) | rank<<11
    #pragma unroll
    for (int k = 0; k < P1_EPT; ++k) {
        const int e = e0 + k * 256;  // coalesced stream per iteration
        if (e < N_EDGES) {
            const int src = ei[e];
            const int dst = ei[N_EDGES + e];
            const int bkt = dst >> 6;
            const int rank = atomicAdd(&cnt[bkt], 1);
            pk[k]   = (unsigned)src | ((unsigned)(dst & 63) << 17);
            meta[k] = bkt | (rank << 11);
        } else {
            meta[k] = -1;
        }
    }
    __syncthreads();

    for (int i = tid; i < NBKT; i += 256) {
        const int c = cnt[i];
        base[i] = c ? atomicAdd(&cursor[i * 16], c) : 0;
    }
    __syncthreads();

    #pragma unroll
    for (int k = 0; k < P1_EPT; ++k) {
        if (meta[k] >= 0) {
            const int bkt = meta[k] & 2047;
            const int idx = base[bkt] + (meta[k] >> 11);
            if (idx < BCAP)
                bbuf[(size_t)bkt * BCAP + idx] = pk[k];
        }
    }
}

// ---------------------------------------------------------------------------
// Kernel 3: fused per-bucket aggregation. One block per bucket (1563 blocks,
// 6252 waves). Bucket edge list staged to LDS once; 4-lane groups process 8
// edges per trip with all 8 y-row loads issued before use (8-deep MLP);
// 64x32 f32 LDS accumulator with rotated atomics (2-way bank alias = free).
// ---------------------------------------------------------------------------
__global__ __launch_bounds__(256) void p2_aggregate(
    const int* __restrict__ cursor,
    const unsigned* __restrict__ bbuf,
    const unsigned* __restrict__ y,
    float* __restrict__ out)
{
    __shared__ float acc[NPB * F_OUT];              // 8 KB
    __shared__ __align__(16) unsigned sE[BCAP];     // 9.5 KB
    const int tid = threadIdx.x;
    const int b = blockIdx.x;

    int nE = cursor[b * 16];
    if (nE > BCAP) nE = BCAP;

    // stage edges to LDS (coalesced uint4)
    {
        const uint4* bb4 = reinterpret_cast<const uint4*>(bbuf + (size_t)b * BCAP);
        uint4* sE4 = reinterpret_cast<uint4*>(sE);
        const int n4 = (nE + 3) >> 2;
        for (int i = tid; i < n4; i += 256) sE4[i] = bb4[i];
    }
    for (int i = tid; i < NPB * F_OUT; i += 256) acc[i] = 0.0f;
    __syncthreads();

    const int g = tid >> 2;     // group 0..63
    const int c = tid & 3;      // uint4 chunk of the 64B row
    const int rot = g & 7;

    for (int i0 = g * 8; i0 < nE; i0 += 512) {
        // 1) pull 8 packed edges from LDS (broadcast within group)
        unsigned w[8];
        #pragma unroll
        for (int j = 0; j < 8; ++j)
            w[j] = (i0 + j < nE) ? sE[i0 + j] : 0u;

        // 2) issue all 8 independent y-row loads (16B/lane, 64B/group)
        uint4 q[8];
        #pragma unroll
        for (int j = 0; j < 8; ++j) {
            const int src = (int)(w[j] & 0x1FFFFu);
            q[j] = reinterpret_cast<const uint4*>(y + (size_t)src * 16)[c];
        }

        // 3) accumulate into LDS (rotated element order: 2-way bank alias)
        #pragma unroll
        for (int j = 0; j < 8; ++j) {
            if (i0 + j < nE) {
                const int dl = (int)((w[j] >> 17) & 63u);
                const unsigned qq[4] = {q[j].x, q[j].y, q[j].z, q[j].w};
                float* arow = acc + dl * F_OUT + c * 8;
                #pragma unroll
                for (int k = 0; k < 8; ++k) {
                    const int kk = (k + rot) & 7;
                    const unsigned u = qq[kk >> 1];
                    const float f = (kk & 1) ? __uint_as_float(u & 0xFFFF0000u)
                                             : __uint_as_float(u << 16);
                    atomicAdd(&arow[kk], f);
                }
            }
        }
    }
    __syncthreads();

    const int vbase = b * NPB;
    const int nrows = min(NPB, N_NODES - vbase);
    const int nflt4 = nrows * (F_OUT / 4);
    float4* o4 = reinterpret_cast<float4*>(out + (size_t)vbase * F_OUT);
    const float4* a4 = reinterpret_cast<const float4*>(acc);
    for (int i = tid; i < nflt4; i += 256) o4[i] = a4[i];
}

extern "C" void kernel_launch(void* const* d_in, const int* in_sizes, int n_in,
                              void* d_out, int out_size, void* d_ws, size_t ws_size,
                              hipStream_t stream) {
    const float* x       = (const float*)d_in[0];
    const float* scalars = (const float*)d_in[1];
    const int*   ei      = (const int*)d_in[2];
    const float* W1      = (const float*)d_in[3];
    const float* b1      = (const float*)d_in[4];
    const float* W2      = (const float*)d_in[5];
    const float* b2      = (const float*)d_in[6];
    float* out = (float*)d_out;

    // Workspace layout (64B aligned), total ~21.7 MB
    char* ws = (char*)d_ws;
    unsigned* y      = (unsigned*)ws;                    //  6,400,000 B
    int*      cursor = (int*)(ws + 6400000);             //    100,032 B (1563*64)
    unsigned* bbuf   = (unsigned*)(ws + 6500032);        // 15,204,864 B (1563*2432*4)

    // 1) per-node MLP -> bf16 y
    node_mlp_kernel<<<(N_NODES + 255) / 256, 256, 0, stream>>>(
        x, scalars, W1, b1, W2, b2, y);

    // 2) zero bucket cursors
    hipMemsetAsync(cursor, 0, (size_t)NBKT * 16 * sizeof(int), stream);

    // 3) partition edges into buckets
    p1_partition<<<P1_BLOCKS, 256, 0, stream>>>(ei, cursor, bbuf);

    // 4) fused per-bucket gather + accumulate + write
    p2_aggregate<<<NBKT, 256, 0, stream>>>(cursor, bbuf, y, out);
}

// Round 6
// 140.853 us; speedup vs baseline: 5.5418x; 4.9384x over previous
//
#include <hip/hip_runtime.h>

#define N_NODES 100000
#define N_EDGES 3200000
#define F_X 24
#define F_S 8
#define D_IN 32   // F_X + F_S
#define H_DIM 64
#define F_OUT 32

#define NPB 64                   // nodes per bucket (bkt = dst>>6)
#define NBKT 1563                // ceil(100000/64); last bucket has 32 nodes
#define BCAP 2432                // per-bucket capacity (mean 2048 + ~8.5 sigma)
#define P1_EPT 32                // edges per thread in partition
#define P1_EPB (256 * P1_EPT)    // 8192 edges per block
#define P1_BLOCKS ((N_EDGES + P1_EPB - 1) / P1_EPB)   // 391

// float -> bf16 (round-to-nearest-even), returns low 16 bits
__device__ __forceinline__ unsigned bf16_rne(float f) {
    unsigned u = __float_as_uint(f);
    return (u + 0x7fffu + ((u >> 16) & 1u)) >> 16;
}

// ---------------------------------------------------------------------------
// Kernel 1: per-node MLP -> bf16 y table ([N_NODES, 32] bf16 = 16 uints/row)
// ---------------------------------------------------------------------------
__global__ __launch_bounds__(256) void node_mlp_kernel(
    const float* __restrict__ x, const float* __restrict__ scalars,
    const float* __restrict__ W1, const float* __restrict__ b1,
    const float* __restrict__ W2, const float* __restrict__ b2,
    unsigned* __restrict__ y)
{
    __shared__ float sW1[D_IN * H_DIM];
    __shared__ float sW2[H_DIM * F_OUT];
    __shared__ float sb1[H_DIM];
    __shared__ float sb2[F_OUT];
    __shared__ float ss[F_S];

    const int tid = threadIdx.x;
    for (int i = tid; i < D_IN * H_DIM; i += 256) sW1[i] = W1[i];
    for (int i = tid; i < H_DIM * F_OUT; i += 256) sW2[i] = W2[i];
    if (tid < H_DIM)  sb1[tid] = b1[tid];
    if (tid < F_OUT)  sb2[tid] = b2[tid];
    if (tid < F_S)    ss[tid]  = scalars[tid];
    __syncthreads();

    const int v = blockIdx.x * 256 + tid;
    if (v >= N_NODES) return;

    float h[D_IN];
    const float4* xr = reinterpret_cast<const float4*>(x + (size_t)v * F_X);
    #pragma unroll
    for (int i = 0; i < F_X / 4; ++i) {
        float4 t = xr[i];
        h[i * 4 + 0] = t.x; h[i * 4 + 1] = t.y;
        h[i * 4 + 2] = t.z; h[i * 4 + 3] = t.w;
    }
    #pragma unroll
    for (int i = 0; i < F_S; ++i) h[F_X + i] = ss[i];

    float hid[H_DIM];
    #pragma unroll
    for (int l = 0; l < H_DIM; ++l) hid[l] = sb1[l];
    #pragma unroll
    for (int k = 0; k < D_IN; ++k) {
        const float hk = h[k];
        #pragma unroll
        for (int l = 0; l < H_DIM; ++l)
            hid[l] = fmaf(hk, sW1[k * H_DIM + l], hid[l]);
    }
    #pragma unroll
    for (int l = 0; l < H_DIM; ++l) hid[l] = fmaxf(hid[l], 0.0f);

    float o[F_OUT];
    #pragma unroll
    for (int j = 0; j < F_OUT; ++j) o[j] = sb2[j];
    #pragma unroll
    for (int l = 0; l < H_DIM; ++l) {
        const float hl = hid[l];
        #pragma unroll
        for (int j = 0; j < F_OUT; ++j)
            o[j] = fmaf(hl, sW2[l * F_OUT + j], o[j]);
    }

    unsigned pk[16];
    #pragma unroll
    for (int k = 0; k < 16; ++k)
        pk[k] = bf16_rne(o[2 * k]) | (bf16_rne(o[2 * k + 1]) << 16);
    uint4* yr = reinterpret_cast<uint4*>(y + (size_t)v * 16);
    #pragma unroll
    for (int q = 0; q < 4; ++q)
        yr[q] = make_uint4(pk[q * 4], pk[q * 4 + 1], pk[q * 4 + 2], pk[q * 4 + 3]);
}

// ---------------------------------------------------------------------------
// Kernel 2: partition edges into 1563 dst-buckets (64 nodes each).
// Block-aggregated reservation: LDS rank assignment, one global atomic per
// (block,bucket) on a line-padded cursor, then packed scatter writes.
// ---------------------------------------------------------------------------
__global__ __launch_bounds__(256) void p1_partition(
    const int* __restrict__ ei,
    int* __restrict__ cursor,        // [NBKT*16] ints, one counter per 64B line
    unsigned* __restrict__ bbuf)     // [NBKT * BCAP] packed edges
{
    __shared__ int cnt[NBKT];
    __shared__ int base[NBKT];
    const int tid = threadIdx.x;
    for (int i = tid; i < NBKT; i += 256) cnt[i] = 0;
    __syncthreads();

    const int e0 = blockIdx.x * P1_EPB + tid;
    unsigned pk[P1_EPT];
    int meta[P1_EPT];                // bkt (11b) | rank<<11
    #pragma unroll
    for (int k = 0; k < P1_EPT; ++k) {
        const int e = e0 + k * 256;  // coalesced stream per iteration
        if (e < N_EDGES) {
            const int src = ei[e];
            const int dst = ei[N_EDGES + e];
            const int bkt = dst >> 6;
            const int rank = atomicAdd(&cnt[bkt], 1);
            pk[k]   = (unsigned)src | ((unsigned)(dst & 63) << 17);
            meta[k] = bkt | (rank << 11);
        } else {
            meta[k] = -1;
        }
    }
    __syncthreads();

    for (int i = tid; i < NBKT; i += 256) {
        const int c = cnt[i];
        base[i] = c ? atomicAdd(&cursor[i * 16], c) : 0;
    }
    __syncthreads();

    #pragma unroll
    for (int k = 0; k < P1_EPT; ++k) {
        if (meta[k] >= 0) {
            const int bkt = meta[k] & 2047;
            const int idx = base[bkt] + (meta[k] >> 11);
            if (idx < BCAP)
                bbuf[(size_t)bkt * BCAP + idx] = pk[k];
        }
    }
}

// ---------------------------------------------------------------------------
// Kernel 3: fused per-bucket aggregation, atomic-free gather.
//   a) stage bucket edges to LDS (coalesced uint4)
//   b) LDS counting sort by local dst (64 segments)
//   c) 4-lane group g owns node g: register-accumulate its segment with
//      8-deep load batches pinned by sched_barrier(0)
//   d) registers -> global out (wave writes 2KB contiguous)
// ---------------------------------------------------------------------------
__global__ __launch_bounds__(256) void p2_aggregate(
    const int* __restrict__ cursor,
    const unsigned* __restrict__ bbuf,
    const unsigned* __restrict__ y,
    float* __restrict__ out)
{
    __shared__ __align__(16) unsigned sE[BCAP];   // 9.5 KB packed edges
    __shared__ unsigned sS[BCAP];                 // 9.5 KB sorted src ids
    __shared__ int cnt[NPB];
    __shared__ int cur[NPB];
    __shared__ int cbase[NPB + 1];

    const int tid = threadIdx.x;
    const int b = blockIdx.x;

    int nE = cursor[b * 16];
    if (nE > BCAP) nE = BCAP;

    // a) stage edges to LDS
    {
        const uint4* bb4 = reinterpret_cast<const uint4*>(bbuf + (size_t)b * BCAP);
        uint4* sE4 = reinterpret_cast<uint4*>(sE);
        const int n4 = (nE + 3) >> 2;
        for (int i = tid; i < n4; i += 256) sE4[i] = bb4[i];
    }
    if (tid < NPB) cnt[tid] = 0;
    __syncthreads();

    // b1) count per local dst
    for (int i = tid; i < nE; i += 256)
        atomicAdd(&cnt[(sE[i] >> 17) & 63u], 1);
    __syncthreads();

    // b2) exclusive scan of 64 counts (wave 0)
    if (tid < 64) {
        const int v = cnt[tid];
        int a = v;
        #pragma unroll
        for (int off = 1; off < 64; off <<= 1) {
            const int u = __shfl_up(a, off, 64);
            if ((tid & 63) >= off) a += u;
        }
        cbase[tid] = a - v;
        cur[tid]   = a - v;
        if (tid == 63) cbase[64] = a;
    }
    __syncthreads();

    // b3) scatter src ids into sorted order
    for (int i = tid; i < nE; i += 256) {
        const unsigned w = sE[i];
        const int pos = atomicAdd(&cur[(w >> 17) & 63u], 1);
        sS[pos] = w & 0x1FFFFu;
    }
    __syncthreads();

    // c) group g accumulates node g's segment in registers
    const int g = tid >> 2;     // 0..63
    const int c = tid & 3;      // uint4 chunk of the 64B y row
    const int beg = cbase[g];
    const int end = cbase[g + 1];

    float acc[8];
    #pragma unroll
    for (int k = 0; k < 8; ++k) acc[k] = 0.0f;

    int i = beg;
    for (; i + 8 <= end; i += 8) {
        unsigned s[8];
        #pragma unroll
        for (int j = 0; j < 8; ++j) s[j] = sS[i + j];

        uint4 q[8];
        #pragma unroll
        for (int j = 0; j < 8; ++j)
            q[j] = reinterpret_cast<const uint4*>(y + (size_t)s[j] * 16)[c];

        // pin: all 8 loads issued before any consume (defeat load sinking)
        __builtin_amdgcn_sched_barrier(0);

        #pragma unroll
        for (int j = 0; j < 8; ++j) {
            const unsigned qq[4] = {q[j].x, q[j].y, q[j].z, q[j].w};
            #pragma unroll
            for (int k = 0; k < 4; ++k) {
                acc[2 * k + 0] += __uint_as_float(qq[k] << 16);
                acc[2 * k + 1] += __uint_as_float(qq[k] & 0xFFFF0000u);
            }
        }
    }
    for (; i < end; ++i) {
        const uint4 q = reinterpret_cast<const uint4*>(y + (size_t)sS[i] * 16)[c];
        const unsigned qq[4] = {q.x, q.y, q.z, q.w};
        #pragma unroll
        for (int k = 0; k < 4; ++k) {
            acc[2 * k + 0] += __uint_as_float(qq[k] << 16);
            acc[2 * k + 1] += __uint_as_float(qq[k] & 0xFFFF0000u);
        }
    }

    // d) write out (wave: 16 consecutive rows x 128B = 2KB contiguous)
    const int v = b * NPB + g;
    if (v < N_NODES) {
        float4* op = reinterpret_cast<float4*>(out + (size_t)v * F_OUT + c * 8);
        op[0] = make_float4(acc[0], acc[1], acc[2], acc[3]);
        op[1] = make_float4(acc[4], acc[5], acc[6], acc[7]);
    }
}

extern "C" void kernel_launch(void* const* d_in, const int* in_sizes, int n_in,
                              void* d_out, int out_size, void* d_ws, size_t ws_size,
                              hipStream_t stream) {
    const float* x       = (const float*)d_in[0];
    const float* scalars = (const float*)d_in[1];
    const int*   ei      = (const int*)d_in[2];
    const float* W1      = (const float*)d_in[3];
    const float* b1      = (const float*)d_in[4];
    const float* W2      = (const float*)d_in[5];
    const float* b2      = (const float*)d_in[6];
    float* out = (float*)d_out;

    // Workspace layout (64B aligned), total ~21.7 MB
    char* ws = (char*)d_ws;
    unsigned* y      = (unsigned*)ws;                    //  6,400,000 B
    int*      cursor = (int*)(ws + 6400000);             //    100,032 B (1563*64)
    unsigned* bbuf   = (unsigned*)(ws + 6500032);        // 15,204,864 B (1563*2432*4)

    // 1) per-node MLP -> bf16 y
    node_mlp_kernel<<<(N_NODES + 255) / 256, 256, 0, stream>>>(
        x, scalars, W1, b1, W2, b2, y);

    // 2) zero bucket cursors
    hipMemsetAsync(cursor, 0, (size_t)NBKT * 16 * sizeof(int), stream);

    // 3) partition edges into buckets
    p1_partition<<<P1_BLOCKS, 256, 0, stream>>>(ei, cursor, bbuf);

    // 4) fused per-bucket sort + gather + write (atomic-free inner loop)
    p2_aggregate<<<NBKT, 256, 0, stream>>>(cursor, bbuf, y, out);
}

// Round 7
// 132.348 us; speedup vs baseline: 5.8979x; 1.0643x over previous
//
#include <hip/hip_runtime.h>

#define N_NODES 100000
#define N_EDGES 3200000
#define F_X 24
#define F_S 8
#define D_IN 32   // F_X + F_S
#define H_DIM 64
#define F_OUT 32

#define NPB 64                   // nodes per bucket (bkt = dst>>6)
#define NBKT 1563                // ceil(100000/64); last bucket has 32 nodes
#define BCAP 2432                // per-bucket capacity (mean 2048 + ~8.5 sigma)
#define P1_THREADS 1024
#define P1_EPT 8                 // edges per thread in partition
#define P1_EPB (P1_THREADS * P1_EPT)                  // 8192 edges per block
#define P1_BLOCKS ((N_EDGES + P1_EPB - 1) / P1_EPB)   // 391

// float -> bf16 (round-to-nearest-even), returns low 16 bits
__device__ __forceinline__ unsigned bf16_rne(float f) {
    unsigned u = __float_as_uint(f);
    return (u + 0x7fffu + ((u >> 16) & 1u)) >> 16;
}

// ---------------------------------------------------------------------------
// Kernel 1: per-node MLP -> bf16 y table ([N_NODES, 32] bf16 = 16 uints/row)
// ---------------------------------------------------------------------------
__global__ __launch_bounds__(256) void node_mlp_kernel(
    const float* __restrict__ x, const float* __restrict__ scalars,
    const float* __restrict__ W1, const float* __restrict__ b1,
    const float* __restrict__ W2, const float* __restrict__ b2,
    unsigned* __restrict__ y)
{
    __shared__ float sW1[D_IN * H_DIM];
    __shared__ float sW2[H_DIM * F_OUT];
    __shared__ float sb1[H_DIM];
    __shared__ float sb2[F_OUT];
    __shared__ float ss[F_S];

    const int tid = threadIdx.x;
    for (int i = tid; i < D_IN * H_DIM; i += 256) sW1[i] = W1[i];
    for (int i = tid; i < H_DIM * F_OUT; i += 256) sW2[i] = W2[i];
    if (tid < H_DIM)  sb1[tid] = b1[tid];
    if (tid < F_OUT)  sb2[tid] = b2[tid];
    if (tid < F_S)    ss[tid]  = scalars[tid];
    __syncthreads();

    const int v = blockIdx.x * 256 + tid;
    if (v >= N_NODES) return;

    float h[D_IN];
    const float4* xr = reinterpret_cast<const float4*>(x + (size_t)v * F_X);
    #pragma unroll
    for (int i = 0; i < F_X / 4; ++i) {
        float4 t = xr[i];
        h[i * 4 + 0] = t.x; h[i * 4 + 1] = t.y;
        h[i * 4 + 2] = t.z; h[i * 4 + 3] = t.w;
    }
    #pragma unroll
    for (int i = 0; i < F_S; ++i) h[F_X + i] = ss[i];

    float hid[H_DIM];
    #pragma unroll
    for (int l = 0; l < H_DIM; ++l) hid[l] = sb1[l];
    #pragma unroll
    for (int k = 0; k < D_IN; ++k) {
        const float hk = h[k];
        #pragma unroll
        for (int l = 0; l < H_DIM; ++l)
            hid[l] = fmaf(hk, sW1[k * H_DIM + l], hid[l]);
    }
    #pragma unroll
    for (int l = 0; l < H_DIM; ++l) hid[l] = fmaxf(hid[l], 0.0f);

    float o[F_OUT];
    #pragma unroll
    for (int j = 0; j < F_OUT; ++j) o[j] = sb2[j];
    #pragma unroll
    for (int l = 0; l < H_DIM; ++l) {
        const float hl = hid[l];
        #pragma unroll
        for (int j = 0; j < F_OUT; ++j)
            o[j] = fmaf(hl, sW2[l * F_OUT + j], o[j]);
    }

    unsigned pk[16];
    #pragma unroll
    for (int k = 0; k < 16; ++k)
        pk[k] = bf16_rne(o[2 * k]) | (bf16_rne(o[2 * k + 1]) << 16);
    uint4* yr = reinterpret_cast<uint4*>(y + (size_t)v * 16);
    #pragma unroll
    for (int q = 0; q < 4; ++q)
        yr[q] = make_uint4(pk[q * 4], pk[q * 4 + 1], pk[q * 4 + 2], pk[q * 4 + 3]);
}

// ---------------------------------------------------------------------------
// Kernel 2: partition edges into 1563 dst-buckets (64 nodes each).
// 1024 threads/block for latency hiding; block-aggregated reservation:
// LDS rank assignment, one global atomic per (block,bucket) on a line-padded
// cursor, then packed scatter writes.
// ---------------------------------------------------------------------------
__global__ __launch_bounds__(P1_THREADS) void p1_partition(
    const int* __restrict__ ei,
    int* __restrict__ cursor,        // [NBKT*16] ints, one counter per 64B line
    unsigned* __restrict__ bbuf)     // [NBKT * BCAP] packed edges
{
    __shared__ int cnt[NBKT];
    __shared__ int base[NBKT];
    const int tid = threadIdx.x;
    for (int i = tid; i < NBKT; i += P1_THREADS) cnt[i] = 0;
    __syncthreads();

    const int e0 = blockIdx.x * P1_EPB + tid;
    unsigned pk[P1_EPT];
    int meta[P1_EPT];                // bkt (11b) | rank<<11
    #pragma unroll
    for (int k = 0; k < P1_EPT; ++k) {
        const int e = e0 + k * P1_THREADS;  // coalesced stream per iteration
        if (e < N_EDGES) {
            const int src = ei[e];
            const int dst = ei[N_EDGES + e];
            const int bkt = dst >> 6;
            const int rank = atomicAdd(&cnt[bkt], 1);
            pk[k]   = (unsigned)src | ((unsigned)(dst & 63) << 17);
            meta[k] = bkt | (rank << 11);
        } else {
            meta[k] = -1;
        }
    }
    __syncthreads();

    for (int i = tid; i < NBKT; i += P1_THREADS) {
        const int c = cnt[i];
        base[i] = c ? atomicAdd(&cursor[i * 16], c) : 0;
    }
    __syncthreads();

    #pragma unroll
    for (int k = 0; k < P1_EPT; ++k) {
        if (meta[k] >= 0) {
            const int bkt = meta[k] & 2047;
            const int idx = base[bkt] + (meta[k] >> 11);
            if (idx < BCAP)
                bbuf[(size_t)bkt * BCAP + idx] = pk[k];
        }
    }
}

// ---------------------------------------------------------------------------
// Kernel 3: fused per-bucket aggregation, atomic-free gather.
//   a) stage bucket edges to LDS (coalesced uint4)
//   b) LDS counting sort by local dst (64 segments)
//   c) 4-lane group g owns node g: register-accumulate its segment with
//      8-deep load batches pinned by sched_barrier(0)
//   d) registers -> global out (wave writes 2KB contiguous)
// ---------------------------------------------------------------------------
__global__ __launch_bounds__(256) void p2_aggregate(
    const int* __restrict__ cursor,
    const unsigned* __restrict__ bbuf,
    const unsigned* __restrict__ y,
    float* __restrict__ out)
{
    __shared__ __align__(16) unsigned sE[BCAP];   // 9.5 KB packed edges
    __shared__ unsigned sS[BCAP];                 // 9.5 KB sorted src ids
    __shared__ int cnt[NPB];
    __shared__ int cur[NPB];
    __shared__ int cbase[NPB + 1];

    const int tid = threadIdx.x;
    const int b = blockIdx.x;

    int nE = cursor[b * 16];
    if (nE > BCAP) nE = BCAP;

    // a) stage edges to LDS
    {
        const uint4* bb4 = reinterpret_cast<const uint4*>(bbuf + (size_t)b * BCAP);
        uint4* sE4 = reinterpret_cast<uint4*>(sE);
        const int n4 = (nE + 3) >> 2;
        for (int i = tid; i < n4; i += 256) sE4[i] = bb4[i];
    }
    if (tid < NPB) cnt[tid] = 0;
    __syncthreads();

    // b1) count per local dst
    for (int i = tid; i < nE; i += 256)
        atomicAdd(&cnt[(sE[i] >> 17) & 63u], 1);
    __syncthreads();

    // b2) exclusive scan of 64 counts (wave 0)
    if (tid < 64) {
        const int v = cnt[tid];
        int a = v;
        #pragma unroll
        for (int off = 1; off < 64; off <<= 1) {
            const int u = __shfl_up(a, off, 64);
            if ((tid & 63) >= off) a += u;
        }
        cbase[tid] = a - v;
        cur[tid]   = a - v;
        if (tid == 63) cbase[64] = a;
    }
    __syncthreads();

    // b3) scatter src ids into sorted order
    for (int i = tid; i < nE; i += 256) {
        const unsigned w = sE[i];
        const int pos = atomicAdd(&cur[(w >> 17) & 63u], 1);
        sS[pos] = w & 0x1FFFFu;
    }
    __syncthreads();

    // c) group g accumulates node g's segment in registers
    const int g = tid >> 2;     // 0..63
    const int c = tid & 3;      // uint4 chunk of the 64B y row
    const int beg = cbase[g];
    const int end = cbase[g + 1];

    float acc[8];
    #pragma unroll
    for (int k = 0; k < 8; ++k) acc[k] = 0.0f;

    int i = beg;
    for (; i + 8 <= end; i += 8) {
        unsigned s[8];
        #pragma unroll
        for (int j = 0; j < 8; ++j) s[j] = sS[i + j];

        uint4 q[8];
        #pragma unroll
        for (int j = 0; j < 8; ++j)
            q[j] = reinterpret_cast<const uint4*>(y + (size_t)s[j] * 16)[c];

        // pin: all 8 loads issued before any consume (defeat load sinking)
        __builtin_amdgcn_sched_barrier(0);

        #pragma unroll
        for (int j = 0; j < 8; ++j) {
            const unsigned qq[4] = {q[j].x, q[j].y, q[j].z, q[j].w};
            #pragma unroll
            for (int k = 0; k < 4; ++k) {
                acc[2 * k + 0] += __uint_as_float(qq[k] << 16);
                acc[2 * k + 1] += __uint_as_float(qq[k] & 0xFFFF0000u);
            }
        }
    }
    for (; i < end; ++i) {
        const uint4 q = reinterpret_cast<const uint4*>(y + (size_t)sS[i] * 16)[c];
        const unsigned qq[4] = {q.x, q.y, q.z, q.w};
        #pragma unroll
        for (int k = 0; k < 4; ++k) {
            acc[2 * k + 0] += __uint_as_float(qq[k] << 16);
            acc[2 * k + 1] += __uint_as_float(qq[k] & 0xFFFF0000u);
        }
    }

    // d) write out (wave: 16 consecutive rows x 128B = 2KB contiguous)
    const int v = b * NPB + g;
    if (v < N_NODES) {
        float4* op = reinterpret_cast<float4*>(out + (size_t)v * F_OUT + c * 8);
        op[0] = make_float4(acc[0], acc[1], acc[2], acc[3]);
        op[1] = make_float4(acc[4], acc[5], acc[6], acc[7]);
    }
}

extern "C" void kernel_launch(void* const* d_in, const int* in_sizes, int n_in,
                              void* d_out, int out_size, void* d_ws, size_t ws_size,
                              hipStream_t stream) {
    const float* x       = (const float*)d_in[0];
    const float* scalars = (const float*)d_in[1];
    const int*   ei      = (const int*)d_in[2];
    const float* W1      = (const float*)d_in[3];
    const float* b1      = (const float*)d_in[4];
    const float* W2      = (const float*)d_in[5];
    const float* b2      = (const float*)d_in[6];
    float* out = (float*)d_out;

    // Workspace layout (64B aligned), total ~21.7 MB
    char* ws = (char*)d_ws;
    unsigned* y      = (unsigned*)ws;                    //  6,400,000 B
    int*      cursor = (int*)(ws + 6400000);             //    100,032 B (1563*64)
    unsigned* bbuf   = (unsigned*)(ws + 6500032);        // 15,204,864 B (1563*2432*4)

    // 1) per-node MLP -> bf16 y
    node_mlp_kernel<<<(N_NODES + 255) / 256, 256, 0, stream>>>(
        x, scalars, W1, b1, W2, b2, y);

    // 2) zero bucket cursors
    hipMemsetAsync(cursor, 0, (size_t)NBKT * 16 * sizeof(int), stream);

    // 3) partition edges into buckets (1024 threads/block for occupancy)
    p1_partition<<<P1_BLOCKS, P1_THREADS, 0, stream>>>(ei, cursor, bbuf);

    // 4) fused per-bucket sort + gather + write (atomic-free inner loop)
    p2_aggregate<<<NBKT, 256, 0, stream>>>(cursor, bbuf, y, out);
}

// Round 8
// 116.148 us; speedup vs baseline: 6.7205x; 1.1395x over previous
//
#include <hip/hip_runtime.h>

#define N_NODES 100000
#define N_EDGES 3200000
#define F_X 24
#define F_S 8
#define D_IN 32   // F_X + F_S
#define H_DIM 64
#define F_OUT 32

#define NPB 256                  // nodes per bucket (bkt = dst>>8)
#define NBKT 391                 // ceil(100000/256); last bucket has 160 nodes
#define BCAP 8832                // per-bucket capacity (mean 8192 + ~7 sigma), mult of 4
#define P1_THREADS 1024
#define P1_EPT 8                 // edges per thread in partition
#define P1_EPB (P1_THREADS * P1_EPT)                  // 8192 edges per block
#define P1_BLOCKS ((N_EDGES + P1_EPB - 1) / P1_EPB)   // 391
#define P2_THREADS 512

// float -> bf16 (round-to-nearest-even), returns low 16 bits
__device__ __forceinline__ unsigned bf16_rne(float f) {
    unsigned u = __float_as_uint(f);
    return (u + 0x7fffu + ((u >> 16) & 1u)) >> 16;
}

// ---------------------------------------------------------------------------
// Kernel 1: per-node MLP -> bf16 y table ([N_NODES, 32] bf16 = 16 uints/row)
// ---------------------------------------------------------------------------
__global__ __launch_bounds__(256) void node_mlp_kernel(
    const float* __restrict__ x, const float* __restrict__ scalars,
    const float* __restrict__ W1, const float* __restrict__ b1,
    const float* __restrict__ W2, const float* __restrict__ b2,
    unsigned* __restrict__ y)
{
    __shared__ float sW1[D_IN * H_DIM];
    __shared__ float sW2[H_DIM * F_OUT];
    __shared__ float sb1[H_DIM];
    __shared__ float sb2[F_OUT];
    __shared__ float ss[F_S];

    const int tid = threadIdx.x;
    for (int i = tid; i < D_IN * H_DIM; i += 256) sW1[i] = W1[i];
    for (int i = tid; i < H_DIM * F_OUT; i += 256) sW2[i] = W2[i];
    if (tid < H_DIM)  sb1[tid] = b1[tid];
    if (tid < F_OUT)  sb2[tid] = b2[tid];
    if (tid < F_S)    ss[tid]  = scalars[tid];
    __syncthreads();

    const int v = blockIdx.x * 256 + tid;
    if (v >= N_NODES) return;

    float h[D_IN];
    const float4* xr = reinterpret_cast<const float4*>(x + (size_t)v * F_X);
    #pragma unroll
    for (int i = 0; i < F_X / 4; ++i) {
        float4 t = xr[i];
        h[i * 4 + 0] = t.x; h[i * 4 + 1] = t.y;
        h[i * 4 + 2] = t.z; h[i * 4 + 3] = t.w;
    }
    #pragma unroll
    for (int i = 0; i < F_S; ++i) h[F_X + i] = ss[i];

    float hid[H_DIM];
    #pragma unroll
    for (int l = 0; l < H_DIM; ++l) hid[l] = sb1[l];
    #pragma unroll
    for (int k = 0; k < D_IN; ++k) {
        const float hk = h[k];
        #pragma unroll
        for (int l = 0; l < H_DIM; ++l)
            hid[l] = fmaf(hk, sW1[k * H_DIM + l], hid[l]);
    }
    #pragma unroll
    for (int l = 0; l < H_DIM; ++l) hid[l] = fmaxf(hid[l], 0.0f);

    float o[F_OUT];
    #pragma unroll
    for (int j = 0; j < F_OUT; ++j) o[j] = sb2[j];
    #pragma unroll
    for (int l = 0; l < H_DIM; ++l) {
        const float hl = hid[l];
        #pragma unroll
        for (int j = 0; j < F_OUT; ++j)
            o[j] = fmaf(hl, sW2[l * F_OUT + j], o[j]);
    }

    unsigned pk[16];
    #pragma unroll
    for (int k = 0; k < 16; ++k)
        pk[k] = bf16_rne(o[2 * k]) | (bf16_rne(o[2 * k + 1]) << 16);
    uint4* yr = reinterpret_cast<uint4*>(y + (size_t)v * 16);
    #pragma unroll
    for (int q = 0; q < 4; ++q)
        yr[q] = make_uint4(pk[q * 4], pk[q * 4 + 1], pk[q * 4 + 2], pk[q * 4 + 3]);
}

// ---------------------------------------------------------------------------
// Kernel 2: partition edges into 391 coarse dst-buckets (256 nodes each).
// Block-aggregated reservation: LDS rank assignment, one global atomic per
// (block,bucket), then packed scatter writes. Runs are ~21 edges (84B) so
// line utilization is good.
// ---------------------------------------------------------------------------
__global__ __launch_bounds__(P1_THREADS) void p1_partition(
    const int* __restrict__ ei,
    int* __restrict__ cursor,        // [NBKT*16] ints, one counter per 64B line
    unsigned* __restrict__ bbuf)     // [NBKT * BCAP] packed edges
{
    __shared__ int cnt[NBKT];
    __shared__ int base[NBKT];
    const int tid = threadIdx.x;
    for (int i = tid; i < NBKT; i += P1_THREADS) cnt[i] = 0;
    __syncthreads();

    const int e0 = blockIdx.x * P1_EPB + tid;
    unsigned pk[P1_EPT];
    int meta[P1_EPT];                // bkt (9b) | rank<<9 (13b)
    #pragma unroll
    for (int k = 0; k < P1_EPT; ++k) {
        const int e = e0 + k * P1_THREADS;  // coalesced stream per iteration
        if (e < N_EDGES) {
            const int src = ei[e];
            const int dst = ei[N_EDGES + e];
            const int bkt = dst >> 8;
            const int rank = atomicAdd(&cnt[bkt], 1);
            pk[k]   = (unsigned)src | ((unsigned)(dst & 255) << 17);
            meta[k] = bkt | (rank << 9);
        } else {
            meta[k] = -1;
        }
    }
    __syncthreads();

    for (int i = tid; i < NBKT; i += P1_THREADS) {
        const int c = cnt[i];
        base[i] = c ? atomicAdd(&cursor[i * 16], c) : 0;
    }
    __syncthreads();

    #pragma unroll
    for (int k = 0; k < P1_EPT; ++k) {
        if (meta[k] >= 0) {
            const int bkt = meta[k] & 511;
            const int idx = base[bkt] + (meta[k] >> 9);
            if (idx < BCAP)
                bbuf[(size_t)bkt * BCAP + idx] = pk[k];
        }
    }
}

// ---------------------------------------------------------------------------
// Kernel 3: fused per-bucket aggregation, atomic-free gather.
//   a) stage bucket edges to LDS (coalesced uint4)
//   b) LDS counting sort by 8-bit local dst (256 segments)
//   c) 2-lane group g owns node g: register-accumulate its segment with
//      depth-4 load batches pinned by sched_barrier(0)
//   d) registers -> global out (wave writes 32 rows x 64B contiguous)
// LDS ~73.8 KB -> 2 blocks/CU; 391 blocks x 512 threads.
// ---------------------------------------------------------------------------
__global__ __launch_bounds__(P2_THREADS) void p2_aggregate(
    const int* __restrict__ cursor,
    const unsigned* __restrict__ bbuf,
    const unsigned* __restrict__ y,
    float* __restrict__ out)
{
    __shared__ __align__(16) unsigned sE[BCAP];   // 34.5 KB packed edges
    __shared__ unsigned sS[BCAP];                 // 34.5 KB sorted src ids
    __shared__ int cnt[NPB];
    __shared__ int cur[NPB];
    __shared__ int cbase[NPB + 1];
    __shared__ int wsum[5];

    const int tid = threadIdx.x;
    const int b = blockIdx.x;

    int nE = cursor[b * 16];
    if (nE > BCAP) nE = BCAP;

    // a) stage edges to LDS
    {
        const uint4* bb4 = reinterpret_cast<const uint4*>(bbuf + (size_t)b * BCAP);
        uint4* sE4 = reinterpret_cast<uint4*>(sE);
        const int n4 = (nE + 3) >> 2;
        for (int i = tid; i < n4; i += P2_THREADS) sE4[i] = bb4[i];
    }
    if (tid < NPB) cnt[tid] = 0;
    __syncthreads();

    // b1) count per local dst
    for (int i = tid; i < nE; i += P2_THREADS)
        atomicAdd(&cnt[(sE[i] >> 17) & 255u], 1);
    __syncthreads();

    // b2) exclusive scan of 256 counts (4 waves shfl-scan + top combine)
    int vcnt = 0, a = 0;
    if (tid < NPB) {
        vcnt = cnt[tid];
        a = vcnt;
        #pragma unroll
        for (int off = 1; off < 64; off <<= 1) {
            const int u = __shfl_up(a, off, 64);
            if ((tid & 63) >= off) a += u;
        }
        if ((tid & 63) == 63) wsum[tid >> 6] = a;
    }
    __syncthreads();
    if (tid == 0) {
        int r = 0;
        #pragma unroll
        for (int w = 0; w < 4; ++w) { const int t = wsum[w]; wsum[w] = r; r += t; }
        wsum[4] = r;
    }
    __syncthreads();
    if (tid < NPB) {
        const int bse = wsum[tid >> 6] + a - vcnt;
        cbase[tid] = bse;
        cur[tid]   = bse;
        if (tid == NPB - 1) cbase[NPB] = wsum[4];
    }
    __syncthreads();

    // b3) scatter src ids into sorted order
    for (int i = tid; i < nE; i += P2_THREADS) {
        const unsigned w = sE[i];
        const int pos = atomicAdd(&cur[(w >> 17) & 255u], 1);
        sS[pos] = w & 0x1FFFFu;
    }
    __syncthreads();

    // c) group g (2 lanes) accumulates node g's segment in registers
    const int g = tid >> 1;     // 0..255
    const int c = tid & 1;      // 32B half of the 64B y row
    const int beg = cbase[g];
    const int end = cbase[g + 1];

    float acc[16];
    #pragma unroll
    for (int k = 0; k < 16; ++k) acc[k] = 0.0f;

    int i = beg;
    for (; i + 4 <= end; i += 4) {
        unsigned s[4];
        #pragma unroll
        for (int j = 0; j < 4; ++j) s[j] = sS[i + j];

        uint4 qa[4], qb[4];
        #pragma unroll
        for (int j = 0; j < 4; ++j) {
            const uint4* r = reinterpret_cast<const uint4*>(y + (size_t)s[j] * 16) + 2 * c;
            qa[j] = r[0];
            qb[j] = r[1];
        }
        // pin: all 8 loads issued before any consume (defeat load sinking)
        __builtin_amdgcn_sched_barrier(0);

        #pragma unroll
        for (int j = 0; j < 4; ++j) {
            const unsigned w0[4] = {qa[j].x, qa[j].y, qa[j].z, qa[j].w};
            const unsigned w1[4] = {qb[j].x, qb[j].y, qb[j].z, qb[j].w};
            #pragma unroll
            for (int k = 0; k < 4; ++k) {
                acc[2 * k + 0] += __uint_as_float(w0[k] << 16);
                acc[2 * k + 1] += __uint_as_float(w0[k] & 0xFFFF0000u);
                acc[8 + 2 * k + 0] += __uint_as_float(w1[k] << 16);
                acc[8 + 2 * k + 1] += __uint_as_float(w1[k] & 0xFFFF0000u);
            }
        }
    }
    for (; i < end; ++i) {
        const uint4* r = reinterpret_cast<const uint4*>(y + (size_t)sS[i] * 16) + 2 * c;
        const uint4 qa = r[0], qb = r[1];
        const unsigned w0[4] = {qa.x, qa.y, qa.z, qa.w};
        const unsigned w1[4] = {qb.x, qb.y, qb.z, qb.w};
        #pragma unroll
        for (int k = 0; k < 4; ++k) {
            acc[2 * k + 0] += __uint_as_float(w0[k] << 16);
            acc[2 * k + 1] += __uint_as_float(w0[k] & 0xFFFF0000u);
            acc[8 + 2 * k + 0] += __uint_as_float(w1[k] << 16);
            acc[8 + 2 * k + 1] += __uint_as_float(w1[k] & 0xFFFF0000u);
        }
    }

    // d) write out: lane owns floats [c*16, c*16+16) of row v
    const int v = b * NPB + g;
    if (v < N_NODES) {
        float4* op = reinterpret_cast<float4*>(out + (size_t)v * F_OUT + c * 16);
        op[0] = make_float4(acc[0],  acc[1],  acc[2],  acc[3]);
        op[1] = make_float4(acc[4],  acc[5],  acc[6],  acc[7]);
        op[2] = make_float4(acc[8],  acc[9],  acc[10], acc[11]);
        op[3] = make_float4(acc[12], acc[13], acc[14], acc[15]);
    }
}

extern "C" void kernel_launch(void* const* d_in, const int* in_sizes, int n_in,
                              void* d_out, int out_size, void* d_ws, size_t ws_size,
                              hipStream_t stream) {
    const float* x       = (const float*)d_in[0];
    const float* scalars = (const float*)d_in[1];
    const int*   ei      = (const int*)d_in[2];
    const float* W1      = (const float*)d_in[3];
    const float* b1      = (const float*)d_in[4];
    const float* W2      = (const float*)d_in[5];
    const float* b2      = (const float*)d_in[6];
    float* out = (float*)d_out;

    // Workspace layout (64B aligned), total ~20.2 MB
    char* ws = (char*)d_ws;
    unsigned* y      = (unsigned*)ws;                    //  6,400,000 B
    int*      cursor = (int*)(ws + 6400000);             //     25,024 B (391*64)
    unsigned* bbuf   = (unsigned*)(ws + 6425024);        // 13,813,248 B (391*8832*4)

    // 1) per-node MLP -> bf16 y
    node_mlp_kernel<<<(N_NODES + 255) / 256, 256, 0, stream>>>(
        x, scalars, W1, b1, W2, b2, y);

    // 2) zero bucket cursors
    hipMemsetAsync(cursor, 0, (size_t)NBKT * 16 * sizeof(int), stream);

    // 3) partition edges into coarse buckets
    p1_partition<<<P1_BLOCKS, P1_THREADS, 0, stream>>>(ei, cursor, bbuf);

    // 4) fused per-bucket sort + gather + write (atomic-free inner loop)
    p2_aggregate<<<NBKT, P2_THREADS, 0, stream>>>(cursor, bbuf, y, out);
}

// Round 9
// 103.748 us; speedup vs baseline: 7.5237x; 1.1195x over previous
//
#include <hip/hip_runtime.h>

#define N_NODES 100000
#define N_EDGES 3200000
#define F_X 24
#define F_S 8
#define D_IN 32   // F_X + F_S
#define H_DIM 64
#define F_OUT 32

#define NPB 256                  // nodes per bucket (bkt = dst>>8)
#define NBKT 391                 // ceil(100000/256); last bucket has 160 nodes
#define BCAP 8832                // per-bucket capacity (mean 8192 + ~7 sigma), mult of 4
#define FUSED_THREADS 1024
#define P1_EPT 8                 // edges per thread in partition
#define P1_EPB (FUSED_THREADS * P1_EPT)               // 8192 edges per block
#define P1_BLOCKS ((N_EDGES + P1_EPB - 1) / P1_EPB)   // 391
#define MLP_BLOCKS ((N_NODES + 255) / 256)            // 391 (256 nodes/block, 4 lanes/node)
#define P2_THREADS 512

// float -> bf16 (round-to-nearest-even), returns low 16 bits
__device__ __forceinline__ unsigned bf16_rne(float f) {
    unsigned u = __float_as_uint(f);
    return (u + 0x7fffu + ((u >> 16) & 1u)) >> 16;
}

// ---------------------------------------------------------------------------
// Fused kernel: blocks [0, P1_BLOCKS) partition edges; blocks
// [P1_BLOCKS, P1_BLOCKS+MLP_BLOCKS) run the node MLP (4 lanes/node).
// The two jobs are data-independent; fusing overlaps p1's memory latency
// with the MLP's VALU/LDS work.
// ---------------------------------------------------------------------------
__global__ __launch_bounds__(FUSED_THREADS) void fused_mlp_p1(
    const float* __restrict__ x, const float* __restrict__ scalars,
    const float* __restrict__ W1, const float* __restrict__ b1,
    const float* __restrict__ W2, const float* __restrict__ b2,
    unsigned* __restrict__ y,
    const int* __restrict__ ei,
    int* __restrict__ cursor,        // [NBKT*16] ints, one counter per 64B line
    unsigned* __restrict__ bbuf)     // [NBKT * BCAP] packed edges
{
    // p1 LDS
    __shared__ int cnt[NBKT];
    __shared__ int basebuf[NBKT];
    // mlp LDS
    __shared__ float sW1[D_IN * H_DIM];   // 8 KB  [k][l]
    __shared__ float sW2[H_DIM * F_OUT];  // 8 KB  [l][j]
    __shared__ float sb1[H_DIM];
    __shared__ float sb2[F_OUT];
    __shared__ float ss[F_S];

    const int tid = threadIdx.x;

    if (blockIdx.x < P1_BLOCKS) {
        // ------------------------- p1: edge partition -------------------------
        for (int i = tid; i < NBKT; i += FUSED_THREADS) cnt[i] = 0;
        __syncthreads();

        const int e0 = blockIdx.x * P1_EPB + tid;
        unsigned pk[P1_EPT];
        int meta[P1_EPT];                // bkt (9b) | rank<<9
        #pragma unroll
        for (int k = 0; k < P1_EPT; ++k) {
            const int e = e0 + k * FUSED_THREADS;   // coalesced stream
            if (e < N_EDGES) {
                const int src = ei[e];
                const int dst = ei[N_EDGES + e];
                const int bkt = dst >> 8;
                const int rank = atomicAdd(&cnt[bkt], 1);
                pk[k]   = (unsigned)src | ((unsigned)(dst & 255) << 17);
                meta[k] = bkt | (rank << 9);
            } else {
                meta[k] = -1;
            }
        }
        __syncthreads();

        for (int i = tid; i < NBKT; i += FUSED_THREADS) {
            const int c = cnt[i];
            basebuf[i] = c ? atomicAdd(&cursor[i * 16], c) : 0;
        }
        __syncthreads();

        #pragma unroll
        for (int k = 0; k < P1_EPT; ++k) {
            if (meta[k] >= 0) {
                const int bkt = meta[k] & 511;
                const int idx = basebuf[bkt] + (meta[k] >> 9);
                if (idx < BCAP)
                    bbuf[(size_t)bkt * BCAP + idx] = pk[k];
            }
        }
    } else {
        // ------------------------- mlp: 4 lanes per node ----------------------
        for (int i = tid; i < D_IN * H_DIM; i += FUSED_THREADS) sW1[i] = W1[i];
        for (int i = tid; i < H_DIM * F_OUT; i += FUSED_THREADS) sW2[i] = W2[i];
        if (tid < H_DIM)  sb1[tid] = b1[tid];
        if (tid < F_OUT)  sb2[tid] = b2[tid];
        if (tid < F_S)    ss[tid]  = scalars[tid];
        __syncthreads();

        const int mb = blockIdx.x - P1_BLOCKS;
        const int v = mb * 256 + (tid >> 2);
        const int c = tid & 3;
        if (v >= N_NODES) return;

        // input row (each of the 4 lanes loads the full row; L1 absorbs)
        float h[D_IN];
        const float4* xr = reinterpret_cast<const float4*>(x + (size_t)v * F_X);
        #pragma unroll
        for (int i = 0; i < F_X / 4; ++i) {
            float4 t = xr[i];
            h[i * 4 + 0] = t.x; h[i * 4 + 1] = t.y;
            h[i * 4 + 2] = t.z; h[i * 4 + 3] = t.w;
        }
        #pragma unroll
        for (int i = 0; i < F_S; ++i) h[F_X + i] = ss[i];

        // layer 1: lane owns hid l in [c*16, c*16+16)
        float hid[16];
        {
            const float4* bb = reinterpret_cast<const float4*>(sb1 + c * 16);
            #pragma unroll
            for (int q = 0; q < 4; ++q) {
                const float4 t = bb[q];
                hid[q * 4 + 0] = t.x; hid[q * 4 + 1] = t.y;
                hid[q * 4 + 2] = t.z; hid[q * 4 + 3] = t.w;
            }
        }
        #pragma unroll
        for (int k = 0; k < D_IN; ++k) {
            const float hk = h[k];
            const float4* wr = reinterpret_cast<const float4*>(sW1 + k * H_DIM + c * 16);
            #pragma unroll
            for (int q = 0; q < 4; ++q) {
                const float4 t = wr[q];
                hid[q * 4 + 0] = fmaf(hk, t.x, hid[q * 4 + 0]);
                hid[q * 4 + 1] = fmaf(hk, t.y, hid[q * 4 + 1]);
                hid[q * 4 + 2] = fmaf(hk, t.z, hid[q * 4 + 2]);
                hid[q * 4 + 3] = fmaf(hk, t.w, hid[q * 4 + 3]);
            }
        }
        #pragma unroll
        for (int l = 0; l < 16; ++l) hid[l] = fmaxf(hid[l], 0.0f);

        // layer 2: lane owns out j in [c*8, c*8+8); iterate all 64 l in 4
        // chunks, pulling each chunk's hid from the owning lane via shfl.
        float op[8];
        #pragma unroll
        for (int t = 0; t < 8; ++t) op[t] = 0.0f;

        #pragma unroll
        for (int d = 0; d < 4; ++d) {
            const int cc = c ^ d;            // chunk owner lane
            float ht[16];
            if (d == 0) {
                #pragma unroll
                for (int t = 0; t < 16; ++t) ht[t] = hid[t];
            } else {
                #pragma unroll
                for (int t = 0; t < 16; ++t) ht[t] = __shfl_xor(hid[t], d);
            }
            const int lbase = cc * 16;
            #pragma unroll
            for (int ll = 0; ll < 16; ++ll) {
                const float hl = ht[ll];
                const float4* wr = reinterpret_cast<const float4*>(
                    sW2 + (lbase + ll) * F_OUT + c * 8);
                const float4 t0 = wr[0], t1 = wr[1];
                op[0] = fmaf(hl, t0.x, op[0]);
                op[1] = fmaf(hl, t0.y, op[1]);
                op[2] = fmaf(hl, t0.z, op[2]);
                op[3] = fmaf(hl, t0.w, op[3]);
                op[4] = fmaf(hl, t1.x, op[4]);
                op[5] = fmaf(hl, t1.y, op[5]);
                op[6] = fmaf(hl, t1.z, op[6]);
                op[7] = fmaf(hl, t1.w, op[7]);
            }
        }
        #pragma unroll
        for (int t = 0; t < 8; ++t) op[t] += sb2[c * 8 + t];

        // pack 8 f32 -> 4 uints (bf16 pairs), store 16B; 4 lanes = 64B row
        unsigned pk4[4];
        #pragma unroll
        for (int t = 0; t < 4; ++t)
            pk4[t] = bf16_rne(op[2 * t]) | (bf16_rne(op[2 * t + 1]) << 16);
        uint4* yr = reinterpret_cast<uint4*>(y + (size_t)v * 16 + c * 4);
        *yr = make_uint4(pk4[0], pk4[1], pk4[2], pk4[3]);
    }
}

// ---------------------------------------------------------------------------
// Kernel 2: fused per-bucket aggregation, atomic-free gather.
//   a) stage bucket edges to LDS (coalesced uint4)
//   b) LDS counting sort by 8-bit local dst (256 segments)
//   c) 2-lane group g owns node g: register-accumulate its segment with
//      depth-4 load batches pinned by sched_barrier(0)
//   d) registers -> global out
// ---------------------------------------------------------------------------
__global__ __launch_bounds__(P2_THREADS) void p2_aggregate(
    const int* __restrict__ cursor,
    const unsigned* __restrict__ bbuf,
    const unsigned* __restrict__ y,
    float* __restrict__ out)
{
    __shared__ __align__(16) unsigned sE[BCAP];   // 34.5 KB packed edges
    __shared__ unsigned sS[BCAP];                 // 34.5 KB sorted src ids
    __shared__ int cnt[NPB];
    __shared__ int cur[NPB];
    __shared__ int cbase[NPB + 1];
    __shared__ int wsum[5];

    const int tid = threadIdx.x;
    const int b = blockIdx.x;

    int nE = cursor[b * 16];
    if (nE > BCAP) nE = BCAP;

    // a) stage edges to LDS
    {
        const uint4* bb4 = reinterpret_cast<const uint4*>(bbuf + (size_t)b * BCAP);
        uint4* sE4 = reinterpret_cast<uint4*>(sE);
        const int n4 = (nE + 3) >> 2;
        for (int i = tid; i < n4; i += P2_THREADS) sE4[i] = bb4[i];
    }
    if (tid < NPB) cnt[tid] = 0;
    __syncthreads();

    // b1) count per local dst
    for (int i = tid; i < nE; i += P2_THREADS)
        atomicAdd(&cnt[(sE[i] >> 17) & 255u], 1);
    __syncthreads();

    // b2) exclusive scan of 256 counts
    int vcnt = 0, a = 0;
    if (tid < NPB) {
        vcnt = cnt[tid];
        a = vcnt;
        #pragma unroll
        for (int off = 1; off < 64; off <<= 1) {
            const int u = __shfl_up(a, off, 64);
            if ((tid & 63) >= off) a += u;
        }
        if ((tid & 63) == 63) wsum[tid >> 6] = a;
    }
    __syncthreads();
    if (tid == 0) {
        int r = 0;
        #pragma unroll
        for (int w = 0; w < 4; ++w) { const int t = wsum[w]; wsum[w] = r; r += t; }
        wsum[4] = r;
    }
    __syncthreads();
    if (tid < NPB) {
        const int bse = wsum[tid >> 6] + a - vcnt;
        cbase[tid] = bse;
        cur[tid]   = bse;
        if (tid == NPB - 1) cbase[NPB] = wsum[4];
    }
    __syncthreads();

    // b3) scatter src ids into sorted order
    for (int i = tid; i < nE; i += P2_THREADS) {
        const unsigned w = sE[i];
        const int pos = atomicAdd(&cur[(w >> 17) & 255u], 1);
        sS[pos] = w & 0x1FFFFu;
    }
    __syncthreads();

    // c) group g (2 lanes) accumulates node g's segment in registers
    const int g = tid >> 1;     // 0..255
    const int c = tid & 1;      // 32B half of the 64B y row
    const int beg = cbase[g];
    const int end = cbase[g + 1];

    float acc[16];
    #pragma unroll
    for (int k = 0; k < 16; ++k) acc[k] = 0.0f;

    int i = beg;
    for (; i + 4 <= end; i += 4) {
        unsigned s[4];
        #pragma unroll
        for (int j = 0; j < 4; ++j) s[j] = sS[i + j];

        uint4 qa[4], qb[4];
        #pragma unroll
        for (int j = 0; j < 4; ++j) {
            const uint4* r = reinterpret_cast<const uint4*>(y + (size_t)s[j] * 16) + 2 * c;
            qa[j] = r[0];
            qb[j] = r[1];
        }
        __builtin_amdgcn_sched_barrier(0);

        #pragma unroll
        for (int j = 0; j < 4; ++j) {
            const unsigned w0[4] = {qa[j].x, qa[j].y, qa[j].z, qa[j].w};
            const unsigned w1[4] = {qb[j].x, qb[j].y, qb[j].z, qb[j].w};
            #pragma unroll
            for (int k = 0; k < 4; ++k) {
                acc[2 * k + 0] += __uint_as_float(w0[k] << 16);
                acc[2 * k + 1] += __uint_as_float(w0[k] & 0xFFFF0000u);
                acc[8 + 2 * k + 0] += __uint_as_float(w1[k] << 16);
                acc[8 + 2 * k + 1] += __uint_as_float(w1[k] & 0xFFFF0000u);
            }
        }
    }
    for (; i < end; ++i) {
        const uint4* r = reinterpret_cast<const uint4*>(y + (size_t)sS[i] * 16) + 2 * c;
        const uint4 qa = r[0], qb = r[1];
        const unsigned w0[4] = {qa.x, qa.y, qa.z, qa.w};
        const unsigned w1[4] = {qb.x, qb.y, qb.z, qb.w};
        #pragma unroll
        for (int k = 0; k < 4; ++k) {
            acc[2 * k + 0] += __uint_as_float(w0[k] << 16);
            acc[2 * k + 1] += __uint_as_float(w0[k] & 0xFFFF0000u);
            acc[8 + 2 * k + 0] += __uint_as_float(w1[k] << 16);
            acc[8 + 2 * k + 1] += __uint_as_float(w1[k] & 0xFFFF0000u);
        }
    }

    // d) write out: lane owns floats [c*16, c*16+16) of row v
    const int v = b * NPB + g;
    if (v < N_NODES) {
        float4* op = reinterpret_cast<float4*>(out + (size_t)v * F_OUT + c * 16);
        op[0] = make_float4(acc[0],  acc[1],  acc[2],  acc[3]);
        op[1] = make_float4(acc[4],  acc[5],  acc[6],  acc[7]);
        op[2] = make_float4(acc[8],  acc[9],  acc[10], acc[11]);
        op[3] = make_float4(acc[12], acc[13], acc[14], acc[15]);
    }
}

extern "C" void kernel_launch(void* const* d_in, const int* in_sizes, int n_in,
                              void* d_out, int out_size, void* d_ws, size_t ws_size,
                              hipStream_t stream) {
    const float* x       = (const float*)d_in[0];
    const float* scalars = (const float*)d_in[1];
    const int*   ei      = (const int*)d_in[2];
    const float* W1      = (const float*)d_in[3];
    const float* b1      = (const float*)d_in[4];
    const float* W2      = (const float*)d_in[5];
    const float* b2      = (const float*)d_in[6];
    float* out = (float*)d_out;

    // Workspace layout (64B aligned), total ~20.2 MB
    char* ws = (char*)d_ws;
    unsigned* y      = (unsigned*)ws;                    //  6,400,000 B
    int*      cursor = (int*)(ws + 6400000);             //     25,024 B (391*64)
    unsigned* bbuf   = (unsigned*)(ws + 6425024);        // 13,813,248 B (391*8832*4)

    // 1) zero bucket cursors
    hipMemsetAsync(cursor, 0, (size_t)NBKT * 16 * sizeof(int), stream);

    // 2) fused: edge partition (blocks 0..390) + node MLP (blocks 391..781)
    fused_mlp_p1<<<P1_BLOCKS + MLP_BLOCKS, FUSED_THREADS, 0, stream>>>(
        x, scalars, W1, b1, W2, b2, y, ei, cursor, bbuf);

    // 3) fused per-bucket sort + gather + write (atomic-free inner loop)
    p2_aggregate<<<NBKT, P2_THREADS, 0, stream>>>(cursor, bbuf, y, out);
}

// Round 10
// 89.539 us; speedup vs baseline: 8.7177x; 1.1587x over previous
//
#include <hip/hip_runtime.h>

#define N_NODES 100000
#define N_EDGES 3200000
#define F_X 24
#define F_S 8
#define D_IN 32   // F_X + F_S
#define H_DIM 64
#define F_OUT 32

#define NPB 256                  // nodes per bucket (bkt = dst>>8)
#define NBKT 391                 // ceil(100000/256)
#define BCAP 8960                // p2 staging capacity (mean 8192 + ~8.5 sigma)
#define P1_THREADS 1024
#define P1_EPT 16                // edges per thread in partition
#define P1_EPB (P1_THREADS * P1_EPT)                  // 16384 edges per block
#define P1_BLOCKS ((N_EDGES + P1_EPB - 1) / P1_EPB)   // 196
#define MLP_BLOCKS ((N_NODES + 255) / 256)            // 391 (4 lanes/node, 1024 thr)
#define P2_THREADS 512
#define OFFS_ROW 392             // 391 bucket bases + total

// float -> bf16 (round-to-nearest-even), returns low 16 bits
__device__ __forceinline__ unsigned bf16_rne(float f) {
    unsigned u = __float_as_uint(f);
    return (u + 0x7fffu + ((u >> 16) & 1u)) >> 16;
}

// ---------------------------------------------------------------------------
// Fused kernel.
//  blocks [0, P1_BLOCKS): edge partition — stage 16K edges, LDS counting-sort
//    by coarse bucket, write the sorted block CONTIGUOUSLY (uint4, full lines,
//    no global atomics, exact sizes), plus its bucket-offset row.
//  blocks [P1_BLOCKS, +MLP_BLOCKS): node MLP (4 lanes/node) -> bf16 y.
//  LDS is carved from one union buffer (p1 ~68.7KB / mlp ~16.8KB).
// ---------------------------------------------------------------------------
__global__ __launch_bounds__(P1_THREADS) void fused_mlp_p1(
    const float* __restrict__ x, const float* __restrict__ scalars,
    const float* __restrict__ W1, const float* __restrict__ b1,
    const float* __restrict__ W2, const float* __restrict__ b2,
    unsigned* __restrict__ y,
    const int* __restrict__ ei,
    unsigned* __restrict__ bbuf,     // [P1_BLOCKS * P1_EPB] sorted packed edges
    int* __restrict__ offs_g)        // [P1_BLOCKS][OFFS_ROW] bucket bases + total
{
    __shared__ __align__(16) unsigned char smem[68736];
    const int tid = threadIdx.x;

    if (blockIdx.x < P1_BLOCKS) {
        // ---------------- p1: sort-and-stream edge partition ----------------
        unsigned* sSE  = (unsigned*)smem;            // 65536 B
        int* cnt       = (int*)(smem + 65536);       // 1564 B (391)
        int* runoff    = (int*)(smem + 67104);       // 1568 B (392)
        int* wsum      = (int*)(smem + 68672);       // 64 B (16)

        const int nbase = blockIdx.x * P1_EPB;
        const int nThis = min(P1_EPB, N_EDGES - nbase);

        for (int i = tid; i < NBKT; i += P1_THREADS) cnt[i] = 0;
        __syncthreads();

        unsigned pk[P1_EPT];
        int meta[P1_EPT];                 // bkt (9b) | rank<<9
        #pragma unroll
        for (int k = 0; k < P1_EPT; ++k) {
            const int idx = tid + k * P1_THREADS;   // coalesced stream
            if (idx < nThis) {
                const int e = nbase + idx;
                const int src = ei[e];
                const int dst = ei[N_EDGES + e];
                const int bkt = dst >> 8;
                const int rank = atomicAdd(&cnt[bkt], 1);
                pk[k]   = (unsigned)src | ((unsigned)(dst & 255) << 17);
                meta[k] = bkt | (rank << 9);
            } else {
                meta[k] = -1;
            }
        }
        __syncthreads();

        // exclusive scan of 391 counts (all waves participate, no divergence)
        const int lane = tid & 63, wid = tid >> 6;
        const int cval = (tid < NBKT) ? cnt[tid] : 0;
        int a = cval;
        #pragma unroll
        for (int off = 1; off < 64; off <<= 1) {
            const int u = __shfl_up(a, off, 64);
            if (lane >= off) a += u;
        }
        if (lane == 63) wsum[wid] = a;
        __syncthreads();
        if (tid == 0) {
            int r = 0;
            #pragma unroll
            for (int w = 0; w < 7; ++w) { const int t = wsum[w]; wsum[w] = r; r += t; }
        }
        __syncthreads();
        if (tid <= NBKT) {
            const int bse = wsum[wid] + a - cval;   // tid==NBKT -> total == nThis
            runoff[tid] = bse;
            offs_g[blockIdx.x * OFFS_ROW + tid] = bse;
        }
        __syncthreads();

        // scatter into LDS in bucket-sorted order
        #pragma unroll
        for (int k = 0; k < P1_EPT; ++k) {
            if (meta[k] >= 0)
                sSE[runoff[meta[k] & 511] + (meta[k] >> 9)] = pk[k];
        }
        __syncthreads();

        // stream out: perfectly coalesced uint4 (nThis is a multiple of 4)
        const uint4* s4 = (const uint4*)sSE;
        uint4* b4 = (uint4*)(bbuf + (size_t)blockIdx.x * P1_EPB);
        for (int i = tid; i < (nThis >> 2); i += P1_THREADS) b4[i] = s4[i];
    } else {
        // ------------------------- mlp: 4 lanes per node --------------------
        float* sW1 = (float*)smem;                   // 8192 B  [k][l]
        float* sW2 = (float*)(smem + 8192);          // 8192 B  [l][j]
        float* sb1 = (float*)(smem + 16384);
        float* sb2 = (float*)(smem + 16640);
        float* ss  = (float*)(smem + 16768);

        for (int i = tid; i < D_IN * H_DIM; i += P1_THREADS) sW1[i] = W1[i];
        for (int i = tid; i < H_DIM * F_OUT; i += P1_THREADS) sW2[i] = W2[i];
        if (tid < H_DIM)  sb1[tid] = b1[tid];
        if (tid < F_OUT)  sb2[tid] = b2[tid];
        if (tid < F_S)    ss[tid]  = scalars[tid];
        __syncthreads();

        const int mb = blockIdx.x - P1_BLOCKS;
        const int v = mb * 256 + (tid >> 2);
        const int c = tid & 3;
        if (v >= N_NODES) return;

        float h[D_IN];
        const float4* xr = reinterpret_cast<const float4*>(x + (size_t)v * F_X);
        #pragma unroll
        for (int i = 0; i < F_X / 4; ++i) {
            float4 t = xr[i];
            h[i * 4 + 0] = t.x; h[i * 4 + 1] = t.y;
            h[i * 4 + 2] = t.z; h[i * 4 + 3] = t.w;
        }
        #pragma unroll
        for (int i = 0; i < F_S; ++i) h[F_X + i] = ss[i];

        // layer 1: lane owns hid l in [c*16, c*16+16)
        float hid[16];
        {
            const float4* bb = reinterpret_cast<const float4*>(sb1 + c * 16);
            #pragma unroll
            for (int q = 0; q < 4; ++q) {
                const float4 t = bb[q];
                hid[q * 4 + 0] = t.x; hid[q * 4 + 1] = t.y;
                hid[q * 4 + 2] = t.z; hid[q * 4 + 3] = t.w;
            }
        }
        #pragma unroll
        for (int k = 0; k < D_IN; ++k) {
            const float hk = h[k];
            const float4* wr = reinterpret_cast<const float4*>(sW1 + k * H_DIM + c * 16);
            #pragma unroll
            for (int q = 0; q < 4; ++q) {
                const float4 t = wr[q];
                hid[q * 4 + 0] = fmaf(hk, t.x, hid[q * 4 + 0]);
                hid[q * 4 + 1] = fmaf(hk, t.y, hid[q * 4 + 1]);
                hid[q * 4 + 2] = fmaf(hk, t.z, hid[q * 4 + 2]);
                hid[q * 4 + 3] = fmaf(hk, t.w, hid[q * 4 + 3]);
            }
        }
        #pragma unroll
        for (int l = 0; l < 16; ++l) hid[l] = fmaxf(hid[l], 0.0f);

        // layer 2: lane owns out j in [c*8, c*8+8); shfl hid chunks around
        float op[8];
        #pragma unroll
        for (int t = 0; t < 8; ++t) op[t] = 0.0f;

        #pragma unroll
        for (int d = 0; d < 4; ++d) {
            const int cc = c ^ d;
            float ht[16];
            if (d == 0) {
                #pragma unroll
                for (int t = 0; t < 16; ++t) ht[t] = hid[t];
            } else {
                #pragma unroll
                for (int t = 0; t < 16; ++t) ht[t] = __shfl_xor(hid[t], d);
            }
            const int lbase = cc * 16;
            #pragma unroll
            for (int ll = 0; ll < 16; ++ll) {
                const float hl = ht[ll];
                const float4* wr = reinterpret_cast<const float4*>(
                    sW2 + (lbase + ll) * F_OUT + c * 8);
                const float4 t0 = wr[0], t1 = wr[1];
                op[0] = fmaf(hl, t0.x, op[0]);
                op[1] = fmaf(hl, t0.y, op[1]);
                op[2] = fmaf(hl, t0.z, op[2]);
                op[3] = fmaf(hl, t0.w, op[3]);
                op[4] = fmaf(hl, t1.x, op[4]);
                op[5] = fmaf(hl, t1.y, op[5]);
                op[6] = fmaf(hl, t1.z, op[6]);
                op[7] = fmaf(hl, t1.w, op[7]);
            }
        }
        #pragma unroll
        for (int t = 0; t < 8; ++t) op[t] += sb2[c * 8 + t];

        unsigned pk4[4];
        #pragma unroll
        for (int t = 0; t < 4; ++t)
            pk4[t] = bf16_rne(op[2 * t]) | (bf16_rne(op[2 * t + 1]) << 16);
        uint4* yr = reinterpret_cast<uint4*>(y + (size_t)v * 16 + c * 4);
        *yr = make_uint4(pk4[0], pk4[1], pk4[2], pk4[3]);
    }
}

// ---------------------------------------------------------------------------
// Kernel 2: per-bucket aggregation.
//   a) gather bucket b's 196 contiguous segments (offs column b) into LDS
//   b) LDS counting sort by 8-bit local dst (256 segments)
//   c) 2-lane group g owns node g: register-accumulate with depth-4 pinned
//      load batches
//   d) registers -> global out
// ---------------------------------------------------------------------------
__global__ __launch_bounds__(P2_THREADS) void p2_aggregate(
    const unsigned* __restrict__ bbuf,
    const int* __restrict__ offs_g,
    const unsigned* __restrict__ y,
    float* __restrict__ out)
{
    __shared__ __align__(16) unsigned sE[BCAP];   // 35 KB bucket edges
    __shared__ unsigned sS[BCAP];                 // 35 KB sorted src ids
    __shared__ int segoff[P1_BLOCKS + 1];
    __shared__ int segsrc[P1_BLOCKS];
    __shared__ int cnt[NPB];
    __shared__ int cur[NPB];
    __shared__ int cbase[NPB + 1];
    __shared__ int wsum8[8];
    __shared__ int wsumT[5];

    const int tid = threadIdx.x;
    const int b = blockIdx.x;
    const int lane = tid & 63, wid = tid >> 6;

    // segment table: column b of offs
    int o0 = 0, cval = 0;
    if (tid < P1_BLOCKS) {
        o0   = offs_g[tid * OFFS_ROW + b];
        cval = offs_g[tid * OFFS_ROW + b + 1] - o0;
        segsrc[tid] = o0;
    }
    int a = cval;
    #pragma unroll
    for (int off = 1; off < 64; off <<= 1) {
        const int u = __shfl_up(a, off, 64);
        if (lane >= off) a += u;
    }
    if (lane == 63) wsum8[wid] = a;
    __syncthreads();
    if (tid == 0) {
        int r = 0;
        #pragma unroll
        for (int w = 0; w < 4; ++w) { const int t = wsum8[w]; wsum8[w] = r; r += t; }
    }
    if (tid < NPB) cnt[tid] = 0;
    __syncthreads();
    if (tid <= P1_BLOCKS) segoff[tid] = wsum8[wid] + a - cval;
    __syncthreads();

    int nE = segoff[P1_BLOCKS];
    if (nE > BCAP) nE = BCAP;

    // a) stage: wave w copies segments w, w+8, ... (coalesced chunks)
    for (int i = wid; i < P1_BLOCKS; i += P2_THREADS / 64) {
        const int d0 = segoff[i];
        const int cI = segoff[i + 1] - d0;
        const unsigned* g = bbuf + (size_t)i * P1_EPB + segsrc[i];
        for (int j = lane; j < cI; j += 64) {
            const int dp = d0 + j;
            if (dp < BCAP) sE[dp] = g[j];
        }
    }
    __syncthreads();

    // b1) count per local dst
    for (int i = tid; i < nE; i += P2_THREADS)
        atomicAdd(&cnt[(sE[i] >> 17) & 255u], 1);
    __syncthreads();

    // b2) exclusive scan of 256 counts
    int vcnt = 0, a2 = 0;
    if (tid < NPB) {
        vcnt = cnt[tid];
        a2 = vcnt;
        #pragma unroll
        for (int off = 1; off < 64; off <<= 1) {
            const int u = __shfl_up(a2, off, 64);
            if ((tid & 63) >= off) a2 += u;
        }
        if ((tid & 63) == 63) wsumT[tid >> 6] = a2;
    }
    __syncthreads();
    if (tid == 0) {
        int r = 0;
        #pragma unroll
        for (int w = 0; w < 4; ++w) { const int t = wsumT[w]; wsumT[w] = r; r += t; }
        wsumT[4] = r;
    }
    __syncthreads();
    if (tid < NPB) {
        const int bse = wsumT[tid >> 6] + a2 - vcnt;
        cbase[tid] = bse;
        cur[tid]   = bse;
        if (tid == NPB - 1) cbase[NPB] = wsumT[4];
    }
    __syncthreads();

    // b3) scatter src ids into sorted order
    for (int i = tid; i < nE; i += P2_THREADS) {
        const unsigned w = sE[i];
        const int pos = atomicAdd(&cur[(w >> 17) & 255u], 1);
        sS[pos] = w & 0x1FFFFu;
    }
    __syncthreads();

    // c) group g (2 lanes) accumulates node g's segment in registers
    const int g = tid >> 1;
    const int c = tid & 1;
    const int beg = cbase[g];
    const int end = cbase[g + 1];

    float acc[16];
    #pragma unroll
    for (int k = 0; k < 16; ++k) acc[k] = 0.0f;

    int i = beg;
    for (; i + 4 <= end; i += 4) {
        unsigned s[4];
        #pragma unroll
        for (int j = 0; j < 4; ++j) s[j] = sS[i + j];

        uint4 qa[4], qb[4];
        #pragma unroll
        for (int j = 0; j < 4; ++j) {
            const uint4* r = reinterpret_cast<const uint4*>(y + (size_t)s[j] * 16) + 2 * c;
            qa[j] = r[0];
            qb[j] = r[1];
        }
        __builtin_amdgcn_sched_barrier(0);

        #pragma unroll
        for (int j = 0; j < 4; ++j) {
            const unsigned w0[4] = {qa[j].x, qa[j].y, qa[j].z, qa[j].w};
            const unsigned w1[4] = {qb[j].x, qb[j].y, qb[j].z, qb[j].w};
            #pragma unroll
            for (int k = 0; k < 4; ++k) {
                acc[2 * k + 0] += __uint_as_float(w0[k] << 16);
                acc[2 * k + 1] += __uint_as_float(w0[k] & 0xFFFF0000u);
                acc[8 + 2 * k + 0] += __uint_as_float(w1[k] << 16);
                acc[8 + 2 * k + 1] += __uint_as_float(w1[k] & 0xFFFF0000u);
            }
        }
    }
    for (; i < end; ++i) {
        const uint4* r = reinterpret_cast<const uint4*>(y + (size_t)sS[i] * 16) + 2 * c;
        const uint4 qa = r[0], qb = r[1];
        const unsigned w0[4] = {qa.x, qa.y, qa.z, qa.w};
        const unsigned w1[4] = {qb.x, qb.y, qb.z, qb.w};
        #pragma unroll
        for (int k = 0; k < 4; ++k) {
            acc[2 * k + 0] += __uint_as_float(w0[k] << 16);
            acc[2 * k + 1] += __uint_as_float(w0[k] & 0xFFFF0000u);
            acc[8 + 2 * k + 0] += __uint_as_float(w1[k] << 16);
            acc[8 + 2 * k + 1] += __uint_as_float(w1[k] & 0xFFFF0000u);
        }
    }

    // d) write out: lane owns floats [c*16, c*16+16) of row v
    const int v = b * NPB + g;
    if (v < N_NODES) {
        float4* op = reinterpret_cast<float4*>(out + (size_t)v * F_OUT + c * 16);
        op[0] = make_float4(acc[0],  acc[1],  acc[2],  acc[3]);
        op[1] = make_float4(acc[4],  acc[5],  acc[6],  acc[7]);
        op[2] = make_float4(acc[8],  acc[9],  acc[10], acc[11]);
        op[3] = make_float4(acc[12], acc[13], acc[14], acc[15]);
    }
}

extern "C" void kernel_launch(void* const* d_in, const int* in_sizes, int n_in,
                              void* d_out, int out_size, void* d_ws, size_t ws_size,
                              hipStream_t stream) {
    const float* x       = (const float*)d_in[0];
    const float* scalars = (const float*)d_in[1];
    const int*   ei      = (const int*)d_in[2];
    const float* W1      = (const float*)d_in[3];
    const float* b1      = (const float*)d_in[4];
    const float* W2      = (const float*)d_in[5];
    const float* b2      = (const float*)d_in[6];
    float* out = (float*)d_out;

    // Workspace layout (16B aligned), total ~19.6 MB
    char* ws = (char*)d_ws;
    unsigned* y      = (unsigned*)ws;                    //  6,400,000 B
    unsigned* bbuf   = (unsigned*)(ws + 6400000);        // 12,845,056 B (196*16384*4)
    int*      offs_g = (int*)(ws + 19245056);            //    307,328 B (196*392*4)

    // 1) fused: edge partition (blocks 0..195) + node MLP (blocks 196..586)
    fused_mlp_p1<<<P1_BLOCKS + MLP_BLOCKS, P1_THREADS, 0, stream>>>(
        x, scalars, W1, b1, W2, b2, y, ei, bbuf, offs_g);

    // 2) per-bucket gather + sort + accumulate + write
    p2_aggregate<<<NBKT, P2_THREADS, 0, stream>>>(bbuf, offs_g, y, out);
}